// Round 6
// baseline (274.145 us; speedup 1.0000x reference)
//
#include <hip/hip_runtime.h>
#include <hip/hip_bf16.h>

#define DIM 128

typedef __attribute__((ext_vector_type(8))) short bf16x8;
typedef __attribute__((ext_vector_type(4))) float f32x4;

// ---- ws layout (float offsets) ----  total 17,716,736 floats = 70.9 MB (ws is 512 MB)
#define WS_B12    0        // 128
#define WS_C      128      // 128  (unused now; kept for layout stability)
#define WS_SUMEE  256      // 128
#define WS_S      384      // 1
#define WS_ZB     416      // 64   Z buckets (atomic, 64-way)
#define WS_GEB    512      // 32*128 ge buckets (atomic, 32-way)
#define WS_WBF    4608     // 32768 bf16 (=16384 floats): Wcat[n][k]
#define WS_EEP    20992    // 128*1024 sum_eE partials, [d*1024 + blk]
#define WS_SEP    152064   // 1024 S partials
#define WS_SP     153088   // N
#define WS_E      415232   // N
#define WS_WEXP   677376   // N
#define WS_EBF    939520   // N*128 bf16 (row-major) = 16,777,216 floats (64 MB)

__device__ __forceinline__ unsigned short f2bf(float f) {
    union { float f; unsigned u; } v; v.f = f;
    unsigned r = v.u + 0x7fffu + ((v.u >> 16) & 1u);
    return (unsigned short)(r >> 16);
}

__device__ __forceinline__ float bfbits(unsigned u) {
    union { unsigned u; float f; } v; v.u = u;
    return v.f;
}

// pack two f32 -> one u32 of 2x bf16 (RNE). Compiler emits v_cvt_pk_bf16_f32.
__device__ __forceinline__ unsigned pkbf(float a, float b) {
    union { __hip_bfloat162 h; unsigned u; } cv;
    cv.h = __float22bfloat162_rn(make_float2(a, b));
    return cv.u;
}

// ---------------- K2: one pass over E -> sp, e, bf16(E), per-block {S, sum_eE} partials ----------------
__global__ __launch_bounds__(256) void k2_stats(const float* __restrict__ E,
                                                const float* __restrict__ v,
                                                const float* __restrict__ wpa,
                                                const float* __restrict__ bpa,
                                                const float* __restrict__ Wc1,
                                                const float* __restrict__ Wc2,
                                                const float* __restrict__ bc1,
                                                const float* __restrict__ bc2,
                                                float* __restrict__ ws) {
    __shared__ float red[16][128];
    __shared__ float redS[16];
    int t = threadIdx.x;

    // ---- folded k1: weight conversion + bucket zero-init
    int gid = blockIdx.x * 256 + t;
    unsigned short* wbf_w = (unsigned short*)(ws + WS_WBF);
    if (gid < 32768) {
        int n = gid >> 7, k = gid & 127;
        float val = (n < 128) ? Wc1[n * 128 + k] : Wc2[(n - 128) * 128 + k];
        wbf_w[gid] = f2bf(val);
    }
    if (gid < 4096) ws[WS_GEB + gid] = 0.f;
    if (gid < 128) ws[WS_B12 + gid] = bc1[gid] + bc2[gid];
    if (gid < 64) ws[WS_ZB + gid] = 0.f;

    int wave = t >> 6, lane = t & 63;
    int cl = lane & 15, rs = lane >> 4;
    int row0 = blockIdx.x * 256;
    const float4* E4 = (const float4*)E;
    unsigned short* ebf = (unsigned short*)(ws + WS_EBF);

    float4 va = ((const float4*)v)[cl];
    float4 vb = ((const float4*)v)[16 + cl];
    float4 pa = ((const float4*)wpa)[cl];
    float4 pb = ((const float4*)wpa)[16 + cl];
    float bias = bpa[0];

    float4 acc0 = {0.f, 0.f, 0.f, 0.f}, acc1 = {0.f, 0.f, 0.f, 0.f};
    float se = 0.f;
    float* sp_ws = ws + WS_SP;
    float* e_ws = ws + WS_E;

#pragma unroll 4
    for (int it = 0; it < 16; ++it) {
        int row = row0 + it * 16 + wave * 4 + rs;
        float4 x0 = E4[row * 32 + cl];
        float4 x1 = E4[row * 32 + 16 + cl];
        unsigned p0 = pkbf(x0.x, x0.y);
        unsigned p1 = pkbf(x0.z, x0.w);
        unsigned p2 = pkbf(x1.x, x1.y);
        unsigned p3 = pkbf(x1.z, x1.w);
        *(uint2*)(ebf + (size_t)row * 128 + cl * 4) = make_uint2(p0, p1);
        *(uint2*)(ebf + (size_t)row * 128 + 64 + cl * 4) = make_uint2(p2, p3);

        float dv = x0.x * va.x + x0.y * va.y + x0.z * va.z + x0.w * va.w
                 + x1.x * vb.x + x1.y * vb.y + x1.z * vb.z + x1.w * vb.w;
        float dp = x0.x * pa.x + x0.y * pa.y + x0.z * pa.z + x0.w * pa.w
                 + x1.x * pb.x + x1.y * pb.y + x1.z * pb.z + x1.w * pb.w;
        for (int off = 1; off < 16; off <<= 1) {
            dv += __shfl_xor(dv, off);
            dp += __shfl_xor(dp, off);
        }
        float e = __expf(dp + bias);
        if (cl == 0) {
            sp_ws[row] = dv;
            e_ws[row] = e;
            se += e;
        }
        acc0.x += e * x0.x; acc0.y += e * x0.y; acc0.z += e * x0.z; acc0.w += e * x0.w;
        acc1.x += e * x1.x; acc1.y += e * x1.y; acc1.z += e * x1.z; acc1.w += e * x1.w;
    }
    int rr = wave * 4 + rs;
    float* dst = red[rr];
    dst[cl * 4 + 0] = acc0.x; dst[cl * 4 + 1] = acc0.y;
    dst[cl * 4 + 2] = acc0.z; dst[cl * 4 + 3] = acc0.w;
    dst[64 + cl * 4 + 0] = acc1.x; dst[64 + cl * 4 + 1] = acc1.y;
    dst[64 + cl * 4 + 2] = acc1.z; dst[64 + cl * 4 + 3] = acc1.w;
    if (cl == 0) redS[rr] = se;
    __syncthreads();
    if (t < 128) {
        float s = 0.f;
#pragma unroll
        for (int r = 0; r < 16; ++r) s += red[r][t];
        ws[WS_EEP + t * 1024 + blockIdx.x] = s;
    }
    if (t == 0) {
        float s = 0.f;
#pragma unroll
        for (int r = 0; r < 16; ++r) s += redS[r];
        ws[WS_SEP + blockIdx.x] = s;
    }
}

// ---------------- K2b: reduce partials -> SUMEE[128], S ----------------
__global__ __launch_bounds__(256) void k2b_reduce(float* __restrict__ ws) {
    __shared__ float r4[4];
    int t = threadIdx.x, blk = blockIdx.x;
    const float* src = (blk < 128) ? (ws + WS_EEP + blk * 1024) : (ws + WS_SEP);
    float s = src[t] + src[t + 256] + src[t + 512] + src[t + 768];
    for (int off = 1; off < 64; off <<= 1) s += __shfl_xor(s, off);
    if ((t & 63) == 0) r4[t >> 6] = s;
    __syncthreads();
    if (t == 0) {
        float tot = r4[0] + r4[1] + r4[2] + r4[3];
        if (blk < 128) ws[WS_SUMEE + blk] = tot;
        else ws[WS_S] = tot;
    }
}

// ---------------- K4: TRANSPOSED MFMA GEMM + fused epilogue, 4 tiles/block ----------------
// LDS packed to 38,944 B (< 40 KB) via lifetime-disjoint aliasing of the loop-phase
// scratch (pim/e/dinv/c) with the final-phase scratch (gep/zw): 4 blocks/CU resident
// (was 42,528 B -> 3 blocks/CU -> serial 4th-block tail per CU, ~25% of k4's time).
__global__ __launch_bounds__(512, 4) void k4_main(const float* __restrict__ wvc,
                                                  const float* __restrict__ bvc_p,
                                                  const float* __restrict__ Wc2,
                                                  float* __restrict__ ws) {
    __shared__ unsigned short Elds[2][64 * 136];  // 2 x 17,408 B, row stride 136 shorts
    __shared__ __align__(16) float aux[1032];     // 4,128 B aliased arena:
    // loop-phase:  pim = aux[0..511] ([8][64]); e_l = aux[512..639] ([2][64]);
    //              di_l = aux[640..767] ([2][64]); c_lds = aux[768..895] ([128])
    // final-phase: gep = aux[0..1023] ([8][128]); zw = aux[1024..1031] ([8])
    float* pim_a  = aux;          // pim[wv][x] = pim_a[wv*64 + x]
    float* e_l    = aux + 512;    // e_l[buf*64 + x]
    float* di_l   = aux + 640;
    float* c_lds  = aux + 768;
    float* gep_a  = aux;          // gep[wv][x] = gep_a[wv*128 + x]
    float* zw     = aux + 1024;

    int t = threadIdx.x;
    int w = t >> 6, lane = t & 63, cl = lane & 15, q = lane >> 4;
    int blk = blockIdx.x;
    int row_base = blk * 256;                    // 4 tiles x 64 rows
    const unsigned short* wbf = (const unsigned short*)(ws + WS_WBF);
    const unsigned short* EbBase = (const unsigned short*)(ws + WS_EBF);

    float bvc = bvc_p[0];
    float Sv = ws[WS_S];
    int r0 = w * 8 + q * 2;                      // this lane's 2 rows within a tile (wexp/ge)

    // A fragments (registers): W_c1 rows j = w*16+cl, W_c2 rows 128 + w*16+cl
    bf16x8 aw1[4], aw2[4];
#pragma unroll
    for (int kt = 0; kt < 4; ++kt) {
        aw1[kt] = *(const bf16x8*)(wbf + (w * 16 + cl) * 128 + kt * 32 + q * 8);
        aw2[kt] = *(const bf16x8*)(wbf + (128 + w * 16 + cl) * 128 + kt * 32 + q * 8);
    }

    // per-lane j-row constants: j = w*16 + q*4 + reg  (D row = (lane>>4)*4 + reg)
    float b12r[4], wvr[4];
#pragma unroll
    for (int reg = 0; reg < 4; ++reg) {
        int jr = w * 16 + q * 4 + reg;
        b12r[reg] = ws[WS_B12 + jr];
        wvr[reg] = wvc[jr];
    }

    // folded k3: c[j] = Wc2[j,:] . sumEE
    if (t < 128) {
        const float4* row = (const float4*)(Wc2 + t * 128);
        const float4* se4 = (const float4*)(ws + WS_SUMEE);
        float4 s4 = {0.f, 0.f, 0.f, 0.f};
#pragma unroll
        for (int k = 0; k < 32; ++k) {
            float4 a = row[k], b = se4[k];
            s4.x += a.x * b.x; s4.y += a.y * b.y; s4.z += a.z * b.z; s4.w += a.w * b.w;
        }
        c_lds[t] = s4.x + s4.y + s4.z + s4.w;
    }

    // stage tile 0 -> buf 0
    {
        const unsigned short* Eb0 = EbBase + (size_t)row_base * 128;
        uint4 s0 = *(const uint4*)(Eb0 + t * 8);
        uint4 s1 = *(const uint4*)(Eb0 + (t + 512) * 8);
        int r = t >> 4, c = t & 15;
        *(uint4*)&Elds[0][r * 136 + c * 8] = s0;
        int t1 = t + 512; r = t1 >> 4; c = t1 & 15;
        *(uint4*)&Elds[0][r * 136 + c * 8] = s1;
    }
    if (t < 64) {
        float ev = ws[WS_E + row_base + t];
        e_l[t] = ev;
        di_l[t] = 1.0f / (Sv - ev);
    }
    __syncthreads();

    // per-lane c_j constants (after barrier so c_lds is ready; c_lds dead afterwards)
    float cjr[4];
#pragma unroll
    for (int reg = 0; reg < 4; ++reg) cjr[reg] = c_lds[w * 16 + q * 4 + reg];

    float z_lane = 0.f;
    float acc8[8] = {0.f, 0.f, 0.f, 0.f, 0.f, 0.f, 0.f, 0.f};

    for (int it = 0; it < 4; ++it) {
        int cur = it & 1, nxt = cur ^ 1;
        int trow0 = row_base + it * 64;
        bool has_next = (it < 3);

        // issue next-tile global loads + this tile's sp loads EARLY
        uint4 s0, s1;
        float evN = 0.f;
        if (has_next) {
            const unsigned short* EbN = EbBase + (size_t)(trow0 + 64) * 128;
            s0 = *(const uint4*)(EbN + t * 8);
            s1 = *(const uint4*)(EbN + (t + 512) * 8);
            if (t < 64) evN = ws[WS_E + trow0 + 64 + t];
        }
        float sp0 = ws[WS_SP + trow0 + r0];
        float sp1 = ws[WS_SP + trow0 + r0 + 1];

        // Transposed GEMM: 32 MFMA per wave. D[j, i]: acc[itile][0]=W_c1 rows, [1]=W_c2 rows
        f32x4 acc[4][2];
#pragma unroll
        for (int rt = 0; rt < 4; ++rt) {
            acc[rt][0] = (f32x4){0.f, 0.f, 0.f, 0.f};
            acc[rt][1] = (f32x4){0.f, 0.f, 0.f, 0.f};
        }
#pragma unroll
        for (int rt = 0; rt < 4; ++rt) {       // rt = i-tile (cols of D)
            bf16x8 b[4];
#pragma unroll
            for (int kt = 0; kt < 4; ++kt)
                b[kt] = *(const bf16x8*)&Elds[cur][(rt * 16 + cl) * 136 + kt * 32 + q * 8];
#pragma unroll
            for (int kt = 0; kt < 4; ++kt) {
                acc[rt][0] = __builtin_amdgcn_mfma_f32_16x16x32_bf16(aw1[kt], b[kt], acc[rt][0], 0, 0, 0);
                acc[rt][1] = __builtin_amdgcn_mfma_f32_16x16x32_bf16(aw2[kt], b[kt], acc[rt][1], 0, 0, 0);
            }
        }

        // Epilogue: i = rt*16 + cl (col), j = w*16 + q*4 + reg (row).
        // pi partial over this lane's 4 j's in-register, then 2 shuffles over q-groups.
#pragma unroll
        for (int rt = 0; rt < 4; ++rt) {
            float e_v = e_l[cur * 64 + rt * 16 + cl];
            float di_v = di_l[cur * 64 + rt * 16 + cl];
            float p = 0.f;
#pragma unroll
            for (int reg = 0; reg < 4; ++reg) {
                float h = acc[rt][0][reg] + b12r[reg] + (cjr[reg] - e_v * acc[rt][1][reg]) * di_v;
                p = fmaf(wvr[reg], fmaxf(h, 0.f), p);
            }
            p += __shfl_xor(p, 16);
            p += __shfl_xor(p, 32);
            if (lane < 16) pim_a[w * 64 + rt * 16 + lane] = p;
        }
        __syncthreads();   // B1: pim visible

        // wexp for this lane's 2 rows (sum pi over 8 waves = 8 j-groups)
        float pi0 = 0.f, pi1 = 0.f;
#pragma unroll
        for (int wv = 0; wv < 8; ++wv) {
            pi0 += pim_a[wv * 64 + r0];
            pi1 += pim_a[wv * 64 + r0 + 1];
        }
        float we0 = __expf(sp0 + bvc + pi0);
        float we1 = __expf(sp1 + bvc + pi1);
        if (cl == 0) {
            ws[WS_WEXP + trow0 + r0] = we0;
            ws[WS_WEXP + trow0 + r0 + 1] = we1;
        }
        z_lane += we0 + we1;

#pragma unroll
        for (int rr = 0; rr < 2; ++rr) {
            int r = r0 + rr;
            float wer = rr ? we1 : we0;
            uint4 u = *(const uint4*)&Elds[cur][r * 136 + cl * 8];
            acc8[0] += wer * bfbits(u.x << 16);
            acc8[1] += wer * bfbits(u.x & 0xffff0000u);
            acc8[2] += wer * bfbits(u.y << 16);
            acc8[3] += wer * bfbits(u.y & 0xffff0000u);
            acc8[4] += wer * bfbits(u.z << 16);
            acc8[5] += wer * bfbits(u.z & 0xffff0000u);
            acc8[6] += wer * bfbits(u.w << 16);
            acc8[7] += wer * bfbits(u.w & 0xffff0000u);
        }

        // write next tile into buf[nxt]
        if (has_next) {
            int r = t >> 4, c = t & 15;
            *(uint4*)&Elds[nxt][r * 136 + c * 8] = s0;
            int t1 = t + 512; r = t1 >> 4; c = t1 & 15;
            *(uint4*)&Elds[nxt][r * 136 + c * 8] = s1;
            if (t < 64) {
                e_l[nxt * 64 + t] = evN;
                di_l[nxt * 64 + t] = 1.0f / (Sv - evN);
            }
        }
        __syncthreads();   // B2: buf[nxt] ready; pim safe to reuse; (final) loop-scratch dead
    }

    // final: reduce accumulated Z and ge once per block (aux now reused as gep/zw)
    z_lane += __shfl_xor(z_lane, 16);
    z_lane += __shfl_xor(z_lane, 32);
    if (lane == 0) zw[w] = z_lane;

#pragma unroll
    for (int jj = 0; jj < 8; ++jj) {
        acc8[jj] += __shfl_xor(acc8[jj], 16);
        acc8[jj] += __shfl_xor(acc8[jj], 32);
    }
    if (lane < 16) {
        *(float4*)&gep_a[w * 128 + cl * 8] = (float4){acc8[0], acc8[1], acc8[2], acc8[3]};
        *(float4*)&gep_a[w * 128 + cl * 8 + 4] = (float4){acc8[4], acc8[5], acc8[6], acc8[7]};
    }
    __syncthreads();

    if (t < 128) {
        float tot = 0.f;
#pragma unroll
        for (int wv = 0; wv < 8; ++wv) tot += gep_a[wv * 128 + t];
        atomicAdd(&ws[WS_GEB + (blk & 31) * 128 + t], tot);
    }
    if (t == 128) {
        float zs = zw[0] + zw[1] + zw[2] + zw[3] + zw[4] + zw[5] + zw[6] + zw[7];
        atomicAdd(&ws[WS_ZB + (blk & 63)], zs);
    }
}

// ---------------- K5: normalize + write outputs ----------------
__global__ __launch_bounds__(256) void k5_final(const float* __restrict__ ws,
                                                float* __restrict__ out) {
    int t = threadIdx.x, blk = blockIdx.x;
    float z = ws[WS_ZB + (t & 63)];
    for (int off = 1; off < 64; off <<= 1) z += __shfl_xor(z, off);
    float invZ = 1.0f / z;
    if (blk < 1024) {
        int i = blk * 256 + t;
        out[128 + i] = ws[WS_WEXP + i] * invZ;
    } else if (t < 128) {
        float s = 0.f;
#pragma unroll
        for (int b = 0; b < 32; ++b) s += ws[WS_GEB + b * 128 + t];
        out[t] = s * invZ;
    }
}

extern "C" void kernel_launch(void* const* d_in, const int* in_sizes, int n_in,
                              void* d_out, int out_size, void* d_ws, size_t ws_size,
                              hipStream_t stream) {
    const float* E   = (const float*)d_in[0];
    const float* v   = (const float*)d_in[1];
    const float* Wc1 = (const float*)d_in[2];
    const float* bc1 = (const float*)d_in[3];
    const float* Wc2 = (const float*)d_in[4];
    const float* bc2 = (const float*)d_in[5];
    const float* wpa = (const float*)d_in[6];
    const float* bpa = (const float*)d_in[7];
    const float* wvc = (const float*)d_in[8];
    const float* bvc = (const float*)d_in[9];
    float* ws  = (float*)d_ws;
    float* out = (float*)d_out;

    k2_stats<<<1024, 256, 0, stream>>>(E, v, wpa, bpa, Wc1, Wc2, bc1, bc2, ws);
    k2b_reduce<<<129, 256, 0, stream>>>(ws);
    k4_main<<<1024, 512, 0, stream>>>(wvc, bvc, Wc2, ws);
    k5_final<<<1025, 256, 0, stream>>>(ws, out);
}

// Round 7
// 264.510 us; speedup vs baseline: 1.0364x; 1.0364x over previous
//
#include <hip/hip_runtime.h>
#include <hip/hip_bf16.h>

#define DIM 128

typedef __attribute__((ext_vector_type(8))) short bf16x8;
typedef __attribute__((ext_vector_type(4))) float f32x4;

// ---- ws layout (float offsets) ----  total 17,716,736 floats = 70.9 MB (ws is 512 MB)
#define WS_B12    0        // 128
#define WS_C      128      // 128  (unused now; kept for layout stability)
#define WS_SUMEE  256      // 128
#define WS_S      384      // 1
#define WS_ZB     416      // 64   Z buckets (atomic, 64-way)
#define WS_GEB    512      // 32*128 ge buckets (atomic, 32-way)
#define WS_WBF    4608     // 32768 bf16 (=16384 floats): Wcat[n][k]
#define WS_EEP    20992    // 128*1024 sum_eE partials, [d*1024 + blk]
#define WS_SEP    152064   // 1024 S partials
#define WS_SP     153088   // N
#define WS_E      415232   // N
#define WS_WEXP   677376   // N
#define WS_EBF    939520   // N*128 bf16 (row-major) = 16,777,216 floats (64 MB)

__device__ __forceinline__ unsigned short f2bf(float f) {
    union { float f; unsigned u; } v; v.f = f;
    unsigned r = v.u + 0x7fffu + ((v.u >> 16) & 1u);
    return (unsigned short)(r >> 16);
}

__device__ __forceinline__ float bfbits(unsigned u) {
    union { unsigned u; float f; } v; v.u = u;
    return v.f;
}

// pack two f32 -> one u32 of 2x bf16 (RNE). Compiler emits v_cvt_pk_bf16_f32.
__device__ __forceinline__ unsigned pkbf(float a, float b) {
    union { __hip_bfloat162 h; unsigned u; } cv;
    cv.h = __float22bfloat162_rn(make_float2(a, b));
    return cv.u;
}

// ---------------- K2: one pass over E -> sp, e, bf16(E), per-block {S, sum_eE} partials ----------------
__global__ __launch_bounds__(256) void k2_stats(const float* __restrict__ E,
                                                const float* __restrict__ v,
                                                const float* __restrict__ wpa,
                                                const float* __restrict__ bpa,
                                                const float* __restrict__ Wc1,
                                                const float* __restrict__ Wc2,
                                                const float* __restrict__ bc1,
                                                const float* __restrict__ bc2,
                                                float* __restrict__ ws) {
    __shared__ float red[16][128];
    __shared__ float redS[16];
    int t = threadIdx.x;

    // ---- folded k1: weight conversion + bucket zero-init
    int gid = blockIdx.x * 256 + t;
    unsigned short* wbf_w = (unsigned short*)(ws + WS_WBF);
    if (gid < 32768) {
        int n = gid >> 7, k = gid & 127;
        float val = (n < 128) ? Wc1[n * 128 + k] : Wc2[(n - 128) * 128 + k];
        wbf_w[gid] = f2bf(val);
    }
    if (gid < 4096) ws[WS_GEB + gid] = 0.f;
    if (gid < 128) ws[WS_B12 + gid] = bc1[gid] + bc2[gid];
    if (gid < 64) ws[WS_ZB + gid] = 0.f;

    int wave = t >> 6, lane = t & 63;
    int cl = lane & 15, rs = lane >> 4;
    int row0 = blockIdx.x * 256;
    const float4* E4 = (const float4*)E;
    unsigned short* ebf = (unsigned short*)(ws + WS_EBF);

    float4 va = ((const float4*)v)[cl];
    float4 vb = ((const float4*)v)[16 + cl];
    float4 pa = ((const float4*)wpa)[cl];
    float4 pb = ((const float4*)wpa)[16 + cl];
    float bias = bpa[0];

    float4 acc0 = {0.f, 0.f, 0.f, 0.f}, acc1 = {0.f, 0.f, 0.f, 0.f};
    float se = 0.f;
    float* sp_ws = ws + WS_SP;
    float* e_ws = ws + WS_E;

#pragma unroll 4
    for (int it = 0; it < 16; ++it) {
        int row = row0 + it * 16 + wave * 4 + rs;
        float4 x0 = E4[row * 32 + cl];
        float4 x1 = E4[row * 32 + 16 + cl];
        unsigned p0 = pkbf(x0.x, x0.y);
        unsigned p1 = pkbf(x0.z, x0.w);
        unsigned p2 = pkbf(x1.x, x1.y);
        unsigned p3 = pkbf(x1.z, x1.w);
        *(uint2*)(ebf + (size_t)row * 128 + cl * 4) = make_uint2(p0, p1);
        *(uint2*)(ebf + (size_t)row * 128 + 64 + cl * 4) = make_uint2(p2, p3);

        float dv = x0.x * va.x + x0.y * va.y + x0.z * va.z + x0.w * va.w
                 + x1.x * vb.x + x1.y * vb.y + x1.z * vb.z + x1.w * vb.w;
        float dp = x0.x * pa.x + x0.y * pa.y + x0.z * pa.z + x0.w * pa.w
                 + x1.x * pb.x + x1.y * pb.y + x1.z * pb.z + x1.w * pb.w;
        for (int off = 1; off < 16; off <<= 1) {
            dv += __shfl_xor(dv, off);
            dp += __shfl_xor(dp, off);
        }
        float e = __expf(dp + bias);
        if (cl == 0) {
            sp_ws[row] = dv;
            e_ws[row] = e;
            se += e;
        }
        acc0.x += e * x0.x; acc0.y += e * x0.y; acc0.z += e * x0.z; acc0.w += e * x0.w;
        acc1.x += e * x1.x; acc1.y += e * x1.y; acc1.z += e * x1.z; acc1.w += e * x1.w;
    }
    int rr = wave * 4 + rs;
    float* dst = red[rr];
    dst[cl * 4 + 0] = acc0.x; dst[cl * 4 + 1] = acc0.y;
    dst[cl * 4 + 2] = acc0.z; dst[cl * 4 + 3] = acc0.w;
    dst[64 + cl * 4 + 0] = acc1.x; dst[64 + cl * 4 + 1] = acc1.y;
    dst[64 + cl * 4 + 2] = acc1.z; dst[64 + cl * 4 + 3] = acc1.w;
    if (cl == 0) redS[rr] = se;
    __syncthreads();
    if (t < 128) {
        float s = 0.f;
#pragma unroll
        for (int r = 0; r < 16; ++r) s += red[r][t];
        ws[WS_EEP + t * 1024 + blockIdx.x] = s;
    }
    if (t == 0) {
        float s = 0.f;
#pragma unroll
        for (int r = 0; r < 16; ++r) s += redS[r];
        ws[WS_SEP + blockIdx.x] = s;
    }
}

// ---------------- K2b: reduce partials -> SUMEE[128], S ----------------
__global__ __launch_bounds__(256) void k2b_reduce(float* __restrict__ ws) {
    __shared__ float r4[4];
    int t = threadIdx.x, blk = blockIdx.x;
    const float* src = (blk < 128) ? (ws + WS_EEP + blk * 1024) : (ws + WS_SEP);
    float s = src[t] + src[t + 256] + src[t + 512] + src[t + 768];
    for (int off = 1; off < 64; off <<= 1) s += __shfl_xor(s, off);
    if ((t & 63) == 0) r4[t >> 6] = s;
    __syncthreads();
    if (t == 0) {
        float tot = r4[0] + r4[1] + r4[2] + r4[3];
        if (blk < 128) ws[WS_SUMEE + blk] = tot;
        else ws[WS_S] = tot;
    }
}

// ---------------- K4: TRANSPOSED MFMA GEMM, 4 tiles/block, ONE barrier per tile ----------------
// Triple-buffered Elds + double-buffered pim/ed kill the second per-tile barrier
// (B2) entirely: 7 barriers/block vs 11, waves may drift a full tile apart.
// Depth-2 staging: at iter it we WRITE regs loaded at it-1 (full-iteration latency
// slack) and ISSUE loads for tile it+2. pim stored [64][8] so the wexp-phase read
// is 4x ds_read_b128 instead of 16x b32; e/dinv packed float2 (4x b64 vs 8x b32).
// LDS 58.4 KB: free, occupancy is VGPR-capped at 2 blocks/CU (r6 null proved it).
__global__ __launch_bounds__(512, 4) void k4_main(const float* __restrict__ wvc,
                                                  const float* __restrict__ bvc_p,
                                                  const float* __restrict__ Wc2,
                                                  float* __restrict__ ws) {
    __shared__ unsigned short Elds[3][64 * 136];   // 3 x 17,408 B, row stride 136 shorts
    __shared__ __align__(16) float arena[1544];    // 6,176 B:
    // loop-phase:  pim2 = arena[0..1023]   ([2][64][8], dbuf, b128-readable)
    //              ed   = arena[1024..1407]([3][64][2] = {e, dinv})
    //              c_lds= arena[1408..1535]
    // final-phase: gep  = arena[0..1023]   ([8][128], aliases pim2)
    //              zw   = arena[1536..1543]
    float* pim2  = arena;
    float* ed    = arena + 1024;
    float* c_lds = arena + 1408;
    float* zw    = arena + 1536;
    float* gep_a = arena;

    int t = threadIdx.x;
    int w = t >> 6, lane = t & 63, cl = lane & 15, q = lane >> 4;
    int blk = blockIdx.x;
    int row_base = blk * 256;                    // 4 tiles x 64 rows
    const unsigned short* wbf = (const unsigned short*)(ws + WS_WBF);
    const unsigned short* EbBase = (const unsigned short*)(ws + WS_EBF);

    float bvc = bvc_p[0];
    float Sv = ws[WS_S];
    int r0 = w * 8 + q * 2;                      // this lane's 2 rows within a tile
    int sr = t >> 4, sc = t & 15;                // stage-write coords, chunk t
    int sr1 = (t + 512) >> 4, sc1 = (t + 512) & 15;

    // A fragments (registers): W_c1 rows j = w*16+cl, W_c2 rows 128 + w*16+cl
    bf16x8 aw1[4], aw2[4];
#pragma unroll
    for (int kt = 0; kt < 4; ++kt) {
        aw1[kt] = *(const bf16x8*)(wbf + (w * 16 + cl) * 128 + kt * 32 + q * 8);
        aw2[kt] = *(const bf16x8*)(wbf + (128 + w * 16 + cl) * 128 + kt * 32 + q * 8);
    }

    // per-lane j-row constants: j = w*16 + q*4 + reg
    float b12r[4], wvr[4];
#pragma unroll
    for (int reg = 0; reg < 4; ++reg) {
        int jr = w * 16 + q * 4 + reg;
        b12r[reg] = ws[WS_B12 + jr];
        wvr[reg] = wvc[jr];
    }

    // folded k3: c[j] = Wc2[j,:] . sumEE
    if (t < 128) {
        const float4* row = (const float4*)(Wc2 + t * 128);
        const float4* se4 = (const float4*)(ws + WS_SUMEE);
        float4 s4 = {0.f, 0.f, 0.f, 0.f};
#pragma unroll
        for (int k = 0; k < 32; ++k) {
            float4 a = row[k], b = se4[k];
            s4.x += a.x * b.x; s4.y += a.y * b.y; s4.z += a.z * b.z; s4.w += a.w * b.w;
        }
        c_lds[t] = s4.x + s4.y + s4.z + s4.w;
    }

    // stage tile 0 -> buf 0 (load+write), then issue tile-1 loads (held across barrier)
    {
        const unsigned short* Eb0 = EbBase + (size_t)row_base * 128;
        uint4 a0 = *(const uint4*)(Eb0 + t * 8);
        uint4 a1 = *(const uint4*)(Eb0 + (t + 512) * 8);
        *(uint4*)&Elds[0][sr * 136 + sc * 8] = a0;
        *(uint4*)&Elds[0][sr1 * 136 + sc1 * 8] = a1;
    }
    if (t < 64) {
        float ev = ws[WS_E + row_base + t];
        *(float2*)&ed[t * 2] = make_float2(ev, 1.0f / (Sv - ev));
    }
    uint4 sN0, sN1;
    float evN = 0.f;
    {
        const unsigned short* Eb1 = EbBase + (size_t)(row_base + 64) * 128;
        sN0 = *(const uint4*)(Eb1 + t * 8);
        sN1 = *(const uint4*)(Eb1 + (t + 512) * 8);
        if (t < 64) evN = ws[WS_E + row_base + 64 + t];
    }
    __syncthreads();   // B_pro: buf0/ed0/c_lds visible

    // per-lane c_j constants (c_lds dead afterwards)
    float cjr[4];
#pragma unroll
    for (int reg = 0; reg < 4; ++reg) cjr[reg] = c_lds[w * 16 + q * 4 + reg];

    float z_lane = 0.f;
    float acc8[8] = {0.f, 0.f, 0.f, 0.f, 0.f, 0.f, 0.f, 0.f};

    for (int it = 0; it < 4; ++it) {
        int cur = it % 3;          // 0,1,2,0
        int pb = it & 1;
        int trow0 = row_base + it * 64;

        // write tile it+1 (regs loaded at it-1 / prologue -> full-iter latency slack)
        if (it < 3) {
            int wr = (it + 1) % 3;
            *(uint4*)&Elds[wr][sr * 136 + sc * 8] = sN0;
            *(uint4*)&Elds[wr][sr1 * 136 + sc1 * 8] = sN1;
            if (t < 64) *(float2*)&ed[(wr * 64 + t) * 2] = make_float2(evN, 1.0f / (Sv - evN));
        }
        // issue loads for tile it+2
        if (it < 2) {
            const unsigned short* EbN = EbBase + (size_t)(trow0 + 128) * 128;
            sN0 = *(const uint4*)(EbN + t * 8);
            sN1 = *(const uint4*)(EbN + (t + 512) * 8);
            if (t < 64) evN = ws[WS_E + trow0 + 128 + t];
        }
        float sp0 = ws[WS_SP + trow0 + r0];
        float sp1 = ws[WS_SP + trow0 + r0 + 1];

        // Transposed GEMM: 32 MFMA per wave. D[j,i]: acc[rt][0]=W_c1 rows, [1]=W_c2 rows
        f32x4 acc[4][2];
#pragma unroll
        for (int rt = 0; rt < 4; ++rt) {
            acc[rt][0] = (f32x4){0.f, 0.f, 0.f, 0.f};
            acc[rt][1] = (f32x4){0.f, 0.f, 0.f, 0.f};
        }
#pragma unroll
        for (int rt = 0; rt < 4; ++rt) {       // rt = i-tile (cols of D)
            bf16x8 b[4];
#pragma unroll
            for (int kt = 0; kt < 4; ++kt)
                b[kt] = *(const bf16x8*)&Elds[cur][(rt * 16 + cl) * 136 + kt * 32 + q * 8];
#pragma unroll
            for (int kt = 0; kt < 4; ++kt) {
                acc[rt][0] = __builtin_amdgcn_mfma_f32_16x16x32_bf16(aw1[kt], b[kt], acc[rt][0], 0, 0, 0);
                acc[rt][1] = __builtin_amdgcn_mfma_f32_16x16x32_bf16(aw2[kt], b[kt], acc[rt][1], 0, 0, 0);
            }
        }

        // Epilogue: i = rt*16 + cl (col), j = w*16 + q*4 + reg (row).
#pragma unroll
        for (int rt = 0; rt < 4; ++rt) {
            float2 edv = *(const float2*)&ed[(cur * 64 + rt * 16 + cl) * 2];
            float p = 0.f;
#pragma unroll
            for (int reg = 0; reg < 4; ++reg) {
                float h = acc[rt][0][reg] + b12r[reg] + (cjr[reg] - edv.x * acc[rt][1][reg]) * edv.y;
                p = fmaf(wvr[reg], fmaxf(h, 0.f), p);
            }
            p += __shfl_xor(p, 16);
            p += __shfl_xor(p, 32);
            if (lane < 16) pim2[(pb * 64 + rt * 16 + lane) * 8 + w] = p;
        }
        __syncthreads();   // B1: pim[pb] + Elds[(it+1)%3] visible; sole barrier this tile

        // wexp: rows r0, r0+1 contiguous in pim2 -> 4x float4 reads
        const float4* pr = (const float4*)&pim2[(pb * 64 + r0) * 8];
        float4 Pa = pr[0], Pb = pr[1], Pc = pr[2], Pd = pr[3];
        float pi0 = (Pa.x + Pa.y + Pa.z + Pa.w) + (Pb.x + Pb.y + Pb.z + Pb.w);
        float pi1 = (Pc.x + Pc.y + Pc.z + Pc.w) + (Pd.x + Pd.y + Pd.z + Pd.w);
        float we0 = __expf(sp0 + bvc + pi0);
        float we1 = __expf(sp1 + bvc + pi1);
        if (cl == 0) {
            ws[WS_WEXP + trow0 + r0] = we0;
            ws[WS_WEXP + trow0 + r0 + 1] = we1;
        }
        z_lane += we0 + we1;

#pragma unroll
        for (int rr = 0; rr < 2; ++rr) {
            int r = r0 + rr;
            float wer = rr ? we1 : we0;
            uint4 u = *(const uint4*)&Elds[cur][r * 136 + cl * 8];
            acc8[0] += wer * bfbits(u.x << 16);
            acc8[1] += wer * bfbits(u.x & 0xffff0000u);
            acc8[2] += wer * bfbits(u.y << 16);
            acc8[3] += wer * bfbits(u.y & 0xffff0000u);
            acc8[4] += wer * bfbits(u.z << 16);
            acc8[5] += wer * bfbits(u.z & 0xffff0000u);
            acc8[6] += wer * bfbits(u.w << 16);
            acc8[7] += wer * bfbits(u.w & 0xffff0000u);
        }
        // no trailing barrier: triple-buffered Elds / dbuf pim+ed make next iter's
        // writes WAR-safe (separated from this iter's reads by the NEXT B1)
    }

    __syncthreads();   // all pim/ed reads done -> arena reusable as gep/zw

    // final: reduce accumulated Z and ge once per block
    z_lane += __shfl_xor(z_lane, 16);
    z_lane += __shfl_xor(z_lane, 32);
    if (lane == 0) zw[w] = z_lane;

#pragma unroll
    for (int jj = 0; jj < 8; ++jj) {
        acc8[jj] += __shfl_xor(acc8[jj], 16);
        acc8[jj] += __shfl_xor(acc8[jj], 32);
    }
    if (lane < 16) {
        *(float4*)&gep_a[w * 128 + cl * 8] = (float4){acc8[0], acc8[1], acc8[2], acc8[3]};
        *(float4*)&gep_a[w * 128 + cl * 8 + 4] = (float4){acc8[4], acc8[5], acc8[6], acc8[7]};
    }
    __syncthreads();

    if (t < 128) {
        float tot = 0.f;
#pragma unroll
        for (int wv = 0; wv < 8; ++wv) tot += gep_a[wv * 128 + t];
        atomicAdd(&ws[WS_GEB + (blk & 31) * 128 + t], tot);
    }
    if (t == 128) {
        float zs = zw[0] + zw[1] + zw[2] + zw[3] + zw[4] + zw[5] + zw[6] + zw[7];
        atomicAdd(&ws[WS_ZB + (blk & 63)], zs);
    }
}

// ---------------- K5: normalize + write outputs ----------------
__global__ __launch_bounds__(256) void k5_final(const float* __restrict__ ws,
                                                float* __restrict__ out) {
    int t = threadIdx.x, blk = blockIdx.x;
    float z = ws[WS_ZB + (t & 63)];
    for (int off = 1; off < 64; off <<= 1) z += __shfl_xor(z, off);
    float invZ = 1.0f / z;
    if (blk < 1024) {
        int i = blk * 256 + t;
        out[128 + i] = ws[WS_WEXP + i] * invZ;
    } else if (t < 128) {
        float s = 0.f;
#pragma unroll
        for (int b = 0; b < 32; ++b) s += ws[WS_GEB + b * 128 + t];
        out[t] = s * invZ;
    }
}

extern "C" void kernel_launch(void* const* d_in, const int* in_sizes, int n_in,
                              void* d_out, int out_size, void* d_ws, size_t ws_size,
                              hipStream_t stream) {
    const float* E   = (const float*)d_in[0];
    const float* v   = (const float*)d_in[1];
    const float* Wc1 = (const float*)d_in[2];
    const float* bc1 = (const float*)d_in[3];
    const float* Wc2 = (const float*)d_in[4];
    const float* bc2 = (const float*)d_in[5];
    const float* wpa = (const float*)d_in[6];
    const float* bpa = (const float*)d_in[7];
    const float* wvc = (const float*)d_in[8];
    const float* bvc = (const float*)d_in[9];
    float* ws  = (float*)d_ws;
    float* out = (float*)d_out;

    k2_stats<<<1024, 256, 0, stream>>>(E, v, wpa, bpa, Wc1, Wc2, bc1, bc2, ws);
    k2b_reduce<<<129, 256, 0, stream>>>(ws);
    k4_main<<<1024, 512, 0, stream>>>(wvc, bvc, Wc2, ws);
    k5_final<<<1025, 256, 0, stream>>>(ws, out);
}

// Round 8
// 259.944 us; speedup vs baseline: 1.0546x; 1.0176x over previous
//
#include <hip/hip_runtime.h>
#include <hip/hip_bf16.h>

#define DIM 128

typedef __attribute__((ext_vector_type(8))) short bf16x8;
typedef __attribute__((ext_vector_type(4))) float f32x4;

// ---- ws layout (float offsets) ----  total 17,716,736 floats = 70.9 MB (ws is 512 MB)
#define WS_B12    0        // 128
#define WS_C      128      // 128  (unused now; kept for layout stability)
#define WS_SUMEE  256      // 128
#define WS_S      384      // 1
#define WS_ZB     416      // 64   Z buckets (atomic, 64-way)
#define WS_GEB    512      // 32*128 ge buckets (atomic, 32-way)
#define WS_WBF    4608     // 32768 bf16 (=16384 floats): Wcat[n][k]
#define WS_EEP    20992    // 128*1024 sum_eE partials, [d*1024 + blk]
#define WS_SEP    152064   // 1024 S partials
#define WS_SP     153088   // N
#define WS_E      415232   // N
#define WS_WEXP   677376   // N
#define WS_EBF    939520   // N*128 bf16 (row-major) = 16,777,216 floats (64 MB)

__device__ __forceinline__ unsigned short f2bf(float f) {
    union { float f; unsigned u; } v; v.f = f;
    unsigned r = v.u + 0x7fffu + ((v.u >> 16) & 1u);
    return (unsigned short)(r >> 16);
}

__device__ __forceinline__ float bfbits(unsigned u) {
    union { unsigned u; float f; } v; v.u = u;
    return v.f;
}

// pack two f32 -> one u32 of 2x bf16 (RNE). Compiler emits v_cvt_pk_bf16_f32.
__device__ __forceinline__ unsigned pkbf(float a, float b) {
    union { __hip_bfloat162 h; unsigned u; } cv;
    cv.h = __float22bfloat162_rn(make_float2(a, b));
    return cv.u;
}

// ---------------- K2: one pass over E -> sp, e, bf16(E), per-block {S, sum_eE} partials ----------------
__global__ __launch_bounds__(256) void k2_stats(const float* __restrict__ E,
                                                const float* __restrict__ v,
                                                const float* __restrict__ wpa,
                                                const float* __restrict__ bpa,
                                                const float* __restrict__ Wc1,
                                                const float* __restrict__ Wc2,
                                                const float* __restrict__ bc1,
                                                const float* __restrict__ bc2,
                                                float* __restrict__ ws) {
    __shared__ float red[16][128];
    __shared__ float redS[16];
    int t = threadIdx.x;

    // ---- folded k1: weight conversion + bucket zero-init
    int gid = blockIdx.x * 256 + t;
    unsigned short* wbf_w = (unsigned short*)(ws + WS_WBF);
    if (gid < 32768) {
        int n = gid >> 7, k = gid & 127;
        float val = (n < 128) ? Wc1[n * 128 + k] : Wc2[(n - 128) * 128 + k];
        wbf_w[gid] = f2bf(val);
    }
    if (gid < 4096) ws[WS_GEB + gid] = 0.f;
    if (gid < 128) ws[WS_B12 + gid] = bc1[gid] + bc2[gid];
    if (gid < 64) ws[WS_ZB + gid] = 0.f;

    int wave = t >> 6, lane = t & 63;
    int cl = lane & 15, rs = lane >> 4;
    int row0 = blockIdx.x * 256;
    const float4* E4 = (const float4*)E;
    unsigned short* ebf = (unsigned short*)(ws + WS_EBF);

    float4 va = ((const float4*)v)[cl];
    float4 vb = ((const float4*)v)[16 + cl];
    float4 pa = ((const float4*)wpa)[cl];
    float4 pb = ((const float4*)wpa)[16 + cl];
    float bias = bpa[0];

    float4 acc0 = {0.f, 0.f, 0.f, 0.f}, acc1 = {0.f, 0.f, 0.f, 0.f};
    float se = 0.f;
    float* sp_ws = ws + WS_SP;
    float* e_ws = ws + WS_E;

#pragma unroll 4
    for (int it = 0; it < 16; ++it) {
        int row = row0 + it * 16 + wave * 4 + rs;
        float4 x0 = E4[row * 32 + cl];
        float4 x1 = E4[row * 32 + 16 + cl];
        unsigned p0 = pkbf(x0.x, x0.y);
        unsigned p1 = pkbf(x0.z, x0.w);
        unsigned p2 = pkbf(x1.x, x1.y);
        unsigned p3 = pkbf(x1.z, x1.w);
        *(uint2*)(ebf + (size_t)row * 128 + cl * 4) = make_uint2(p0, p1);
        *(uint2*)(ebf + (size_t)row * 128 + 64 + cl * 4) = make_uint2(p2, p3);

        float dv = x0.x * va.x + x0.y * va.y + x0.z * va.z + x0.w * va.w
                 + x1.x * vb.x + x1.y * vb.y + x1.z * vb.z + x1.w * vb.w;
        float dp = x0.x * pa.x + x0.y * pa.y + x0.z * pa.z + x0.w * pa.w
                 + x1.x * pb.x + x1.y * pb.y + x1.z * pb.z + x1.w * pb.w;
        for (int off = 1; off < 16; off <<= 1) {
            dv += __shfl_xor(dv, off);
            dp += __shfl_xor(dp, off);
        }
        float e = __expf(dp + bias);
        if (cl == 0) {
            sp_ws[row] = dv;
            e_ws[row] = e;
            se += e;
        }
        acc0.x += e * x0.x; acc0.y += e * x0.y; acc0.z += e * x0.z; acc0.w += e * x0.w;
        acc1.x += e * x1.x; acc1.y += e * x1.y; acc1.z += e * x1.z; acc1.w += e * x1.w;
    }
    int rr = wave * 4 + rs;
    float* dst = red[rr];
    dst[cl * 4 + 0] = acc0.x; dst[cl * 4 + 1] = acc0.y;
    dst[cl * 4 + 2] = acc0.z; dst[cl * 4 + 3] = acc0.w;
    dst[64 + cl * 4 + 0] = acc1.x; dst[64 + cl * 4 + 1] = acc1.y;
    dst[64 + cl * 4 + 2] = acc1.z; dst[64 + cl * 4 + 3] = acc1.w;
    if (cl == 0) redS[rr] = se;
    __syncthreads();
    if (t < 128) {
        float s = 0.f;
#pragma unroll
        for (int r = 0; r < 16; ++r) s += red[r][t];
        ws[WS_EEP + t * 1024 + blockIdx.x] = s;
    }
    if (t == 0) {
        float s = 0.f;
#pragma unroll
        for (int r = 0; r < 16; ++r) s += redS[r];
        ws[WS_SEP + blockIdx.x] = s;
    }
}

// ---------------- K2b: reduce partials -> SUMEE[128], S ----------------
__global__ __launch_bounds__(256) void k2b_reduce(float* __restrict__ ws) {
    __shared__ float r4[4];
    int t = threadIdx.x, blk = blockIdx.x;
    const float* src = (blk < 128) ? (ws + WS_EEP + blk * 1024) : (ws + WS_SEP);
    float s = src[t] + src[t + 256] + src[t + 512] + src[t + 768];
    for (int off = 1; off < 64; off <<= 1) s += __shfl_xor(s, off);
    if ((t & 63) == 0) r4[t >> 6] = s;
    __syncthreads();
    if (t == 0) {
        float tot = r4[0] + r4[1] + r4[2] + r4[3];
        if (blk < 128) ws[WS_SUMEE + blk] = tot;
        else ws[WS_S] = tot;
    }
}

// ---------------- K4: 4-wave transposed MFMA GEMM, 4 tiles/block, 1 barrier/tile ----------------
// 4 waves (256 thr); each wave owns TWO j-tile pairs (aw[2][2][4]) so every B-fragment
// ds_read_b128 feeds 4 MFMAs instead of 2 -> total per-CU LDS B-read volume HALVES
// (the dominant k4 pipe: was 8 waves x full 16KB tile re-read). pim[2][64][4]: wexp
// reads one float4 per row (all 4 waves). sp/wexp are float4 (r0 4-aligned).
// VGPR ~230 under __launch_bounds__(256,2): 2 blocks/CU, depth-2 staging retained.
__global__ __launch_bounds__(256, 2) void k4_main(const float* __restrict__ wvc,
                                                  const float* __restrict__ bvc_p,
                                                  const float* __restrict__ Wc2,
                                                  float* __restrict__ ws) {
    __shared__ unsigned short Elds[3][64 * 136];   // 3 x 17,408 B, row stride 136 shorts
    __shared__ __align__(16) float arena[1028];    // 4,112 B:
    // loop-phase:  pim2 = arena[0..511]   ([2][64][4], dbuf, float4-readable)
    //              ed   = arena[512..895] ([3][64][2] = {e, dinv})
    //              c_lds= arena[896..1023]
    // final-phase: gep  = arena[0..511]   ([4][128], aliases pim2)
    //              zw   = arena[1024..1027]
    float* pim2  = arena;
    float* ed    = arena + 512;
    float* c_lds = arena + 896;
    float* zw    = arena + 1024;
    float* gep_a = arena;

    int t = threadIdx.x;
    int w = t >> 6, lane = t & 63, cl = lane & 15, q = lane >> 4;
    int blk = blockIdx.x;
    int row_base = blk * 256;                    // 4 tiles x 64 rows
    const unsigned short* wbf = (const unsigned short*)(ws + WS_WBF);
    const unsigned short* EbBase = (const unsigned short*)(ws + WS_EBF);

    float bvc = bvc_p[0];
    float Sv = ws[WS_S];
    int r0 = w * 16 + q * 4;                     // this lane's 4 rows within a tile
    // stage-write coords for 4 chunks/thread
    int sr0 = t >> 4,           sc0 = t & 15;
    int sr1 = (t + 256) >> 4,   sc1 = (t + 256) & 15;
    int sr2 = (t + 512) >> 4,   sc2 = (t + 512) & 15;
    int sr3 = (t + 768) >> 4,   sc3 = (t + 768) & 15;

    // A fragments: wave w owns j-tiles {2w, 2w+1} for BOTH W_c1 and W_c2
    bf16x8 aw[2][2][4];   // [jt][0=W1,1=W2][kt]
#pragma unroll
    for (int jt = 0; jt < 2; ++jt) {
#pragma unroll
        for (int kt = 0; kt < 4; ++kt) {
            int jrow = w * 32 + jt * 16 + cl;
            aw[jt][0][kt] = *(const bf16x8*)(wbf + jrow * 128 + kt * 32 + q * 8);
            aw[jt][1][kt] = *(const bf16x8*)(wbf + (128 + jrow) * 128 + kt * 32 + q * 8);
        }
    }

    // per-lane j-row constants: j = w*32 + jt*16 + q*4 + reg
    float b12r[2][4], wvr[2][4];
#pragma unroll
    for (int jt = 0; jt < 2; ++jt)
#pragma unroll
        for (int reg = 0; reg < 4; ++reg) {
            int jr = w * 32 + jt * 16 + q * 4 + reg;
            b12r[jt][reg] = ws[WS_B12 + jr];
            wvr[jt][reg] = wvc[jr];
        }

    // folded k3: c[j] = Wc2[j,:] . sumEE
    if (t < 128) {
        const float4* row = (const float4*)(Wc2 + t * 128);
        const float4* se4 = (const float4*)(ws + WS_SUMEE);
        float4 s4 = {0.f, 0.f, 0.f, 0.f};
#pragma unroll
        for (int k = 0; k < 32; ++k) {
            float4 a = row[k], b = se4[k];
            s4.x += a.x * b.x; s4.y += a.y * b.y; s4.z += a.z * b.z; s4.w += a.w * b.w;
        }
        c_lds[t] = s4.x + s4.y + s4.z + s4.w;
    }

    // stage tile 0 -> buf 0 (4 chunks/thread), then issue tile-1 loads (held across barrier)
    {
        const unsigned short* Eb0 = EbBase + (size_t)row_base * 128;
        uint4 a0 = *(const uint4*)(Eb0 + t * 8);
        uint4 a1 = *(const uint4*)(Eb0 + (t + 256) * 8);
        uint4 a2 = *(const uint4*)(Eb0 + (t + 512) * 8);
        uint4 a3 = *(const uint4*)(Eb0 + (t + 768) * 8);
        *(uint4*)&Elds[0][sr0 * 136 + sc0 * 8] = a0;
        *(uint4*)&Elds[0][sr1 * 136 + sc1 * 8] = a1;
        *(uint4*)&Elds[0][sr2 * 136 + sc2 * 8] = a2;
        *(uint4*)&Elds[0][sr3 * 136 + sc3 * 8] = a3;
    }
    if (t < 64) {
        float ev = ws[WS_E + row_base + t];
        *(float2*)&ed[t * 2] = make_float2(ev, 1.0f / (Sv - ev));
    }
    uint4 sN0, sN1, sN2, sN3;
    float evN = 0.f;
    {
        const unsigned short* Eb1 = EbBase + (size_t)(row_base + 64) * 128;
        sN0 = *(const uint4*)(Eb1 + t * 8);
        sN1 = *(const uint4*)(Eb1 + (t + 256) * 8);
        sN2 = *(const uint4*)(Eb1 + (t + 512) * 8);
        sN3 = *(const uint4*)(Eb1 + (t + 768) * 8);
        if (t < 64) evN = ws[WS_E + row_base + 64 + t];
    }
    __syncthreads();   // B_pro: buf0/ed0/c_lds visible

    // per-lane c_j constants (c_lds dead afterwards)
    float cjr[2][4];
#pragma unroll
    for (int jt = 0; jt < 2; ++jt)
#pragma unroll
        for (int reg = 0; reg < 4; ++reg)
            cjr[jt][reg] = c_lds[w * 32 + jt * 16 + q * 4 + reg];

    float z_lane = 0.f;
    float acc8[8] = {0.f, 0.f, 0.f, 0.f, 0.f, 0.f, 0.f, 0.f};

    for (int it = 0; it < 4; ++it) {
        int cur = it % 3;          // 0,1,2,0
        int pb = it & 1;
        int trow0 = row_base + it * 64;

        // write tile it+1 (regs loaded at it-1 / prologue -> full-iter latency slack)
        if (it < 3) {
            int wr = (it + 1) % 3;
            *(uint4*)&Elds[wr][sr0 * 136 + sc0 * 8] = sN0;
            *(uint4*)&Elds[wr][sr1 * 136 + sc1 * 8] = sN1;
            *(uint4*)&Elds[wr][sr2 * 136 + sc2 * 8] = sN2;
            *(uint4*)&Elds[wr][sr3 * 136 + sc3 * 8] = sN3;
            if (t < 64) *(float2*)&ed[(wr * 64 + t) * 2] = make_float2(evN, 1.0f / (Sv - evN));
        }
        // issue loads for tile it+2
        if (it < 2) {
            const unsigned short* EbN = EbBase + (size_t)(trow0 + 128) * 128;
            sN0 = *(const uint4*)(EbN + t * 8);
            sN1 = *(const uint4*)(EbN + (t + 256) * 8);
            sN2 = *(const uint4*)(EbN + (t + 512) * 8);
            sN3 = *(const uint4*)(EbN + (t + 768) * 8);
            if (t < 64) evN = ws[WS_E + trow0 + 128 + t];
        }
        float4 sp4 = *(const float4*)&ws[WS_SP + trow0 + r0];

        // Transposed GEMM: 64 MFMA per wave. D[j,i]: acc[rt][jt][0]=W1, [1]=W2
        f32x4 acc[4][2][2];
#pragma unroll
        for (int rt = 0; rt < 4; ++rt)
#pragma unroll
            for (int jt = 0; jt < 2; ++jt) {
                acc[rt][jt][0] = (f32x4){0.f, 0.f, 0.f, 0.f};
                acc[rt][jt][1] = (f32x4){0.f, 0.f, 0.f, 0.f};
            }
#pragma unroll
        for (int rt = 0; rt < 4; ++rt) {       // rt = i-tile (cols of D)
            bf16x8 b[4];
#pragma unroll
            for (int kt = 0; kt < 4; ++kt)
                b[kt] = *(const bf16x8*)&Elds[cur][(rt * 16 + cl) * 136 + kt * 32 + q * 8];
#pragma unroll
            for (int kt = 0; kt < 4; ++kt) {
                acc[rt][0][0] = __builtin_amdgcn_mfma_f32_16x16x32_bf16(aw[0][0][kt], b[kt], acc[rt][0][0], 0, 0, 0);
                acc[rt][0][1] = __builtin_amdgcn_mfma_f32_16x16x32_bf16(aw[0][1][kt], b[kt], acc[rt][0][1], 0, 0, 0);
                acc[rt][1][0] = __builtin_amdgcn_mfma_f32_16x16x32_bf16(aw[1][0][kt], b[kt], acc[rt][1][0], 0, 0, 0);
                acc[rt][1][1] = __builtin_amdgcn_mfma_f32_16x16x32_bf16(aw[1][1][kt], b[kt], acc[rt][1][1], 0, 0, 0);
            }
        }

        // Epilogue: i = rt*16 + cl (col), j = w*32 + jt*16 + q*4 + reg (row).
#pragma unroll
        for (int rt = 0; rt < 4; ++rt) {
            float2 edv = *(const float2*)&ed[(cur * 64 + rt * 16 + cl) * 2];
            float p = 0.f;
#pragma unroll
            for (int jt = 0; jt < 2; ++jt)
#pragma unroll
                for (int reg = 0; reg < 4; ++reg) {
                    float h = acc[rt][jt][0][reg] + b12r[jt][reg]
                            + (cjr[jt][reg] - edv.x * acc[rt][jt][1][reg]) * edv.y;
                    p = fmaf(wvr[jt][reg], fmaxf(h, 0.f), p);
                }
            p += __shfl_xor(p, 16);
            p += __shfl_xor(p, 32);
            if (lane < 16) pim2[(pb * 64 + rt * 16 + lane) * 4 + w] = p;
        }
        __syncthreads();   // B1: pim[pb] + Elds[(it+1)%3] visible; sole barrier this tile

        // wexp: 4 rows/lane; pim2 row = one float4 (all 4 waves)
        float we[4];
#pragma unroll
        for (int rr = 0; rr < 4; ++rr) {
            float4 P = *(const float4*)&pim2[(pb * 64 + r0 + rr) * 4];
            float pi = (P.x + P.y) + (P.z + P.w);
            float spv = (rr == 0) ? sp4.x : (rr == 1) ? sp4.y : (rr == 2) ? sp4.z : sp4.w;
            we[rr] = __expf(spv + bvc + pi);
            z_lane += we[rr];
        }
        if (cl == 0)
            *(float4*)&ws[WS_WEXP + trow0 + r0] = (float4){we[0], we[1], we[2], we[3]};

#pragma unroll
        for (int rr = 0; rr < 4; ++rr) {
            int r = r0 + rr;
            float wer = we[rr];
            uint4 u = *(const uint4*)&Elds[cur][r * 136 + cl * 8];
            acc8[0] += wer * bfbits(u.x << 16);
            acc8[1] += wer * bfbits(u.x & 0xffff0000u);
            acc8[2] += wer * bfbits(u.y << 16);
            acc8[3] += wer * bfbits(u.y & 0xffff0000u);
            acc8[4] += wer * bfbits(u.z << 16);
            acc8[5] += wer * bfbits(u.z & 0xffff0000u);
            acc8[6] += wer * bfbits(u.w << 16);
            acc8[7] += wer * bfbits(u.w & 0xffff0000u);
        }
        // no trailing barrier: triple-buffered Elds / dbuf pim / triple ed keep next
        // iter's writes WAR-safe (separated from this iter's reads by the NEXT B1)
    }

    __syncthreads();   // all pim/ed reads done -> arena reusable as gep/zw

    // final: reduce accumulated Z and ge once per block
    z_lane += __shfl_xor(z_lane, 16);
    z_lane += __shfl_xor(z_lane, 32);
    if (lane == 0) zw[w] = z_lane;

#pragma unroll
    for (int jj = 0; jj < 8; ++jj) {
        acc8[jj] += __shfl_xor(acc8[jj], 16);
        acc8[jj] += __shfl_xor(acc8[jj], 32);
    }
    if (lane < 16) {
        *(float4*)&gep_a[w * 128 + cl * 8] = (float4){acc8[0], acc8[1], acc8[2], acc8[3]};
        *(float4*)&gep_a[w * 128 + cl * 8 + 4] = (float4){acc8[4], acc8[5], acc8[6], acc8[7]};
    }
    __syncthreads();

    if (t < 128) {
        float tot = gep_a[t] + gep_a[128 + t] + gep_a[256 + t] + gep_a[384 + t];
        atomicAdd(&ws[WS_GEB + (blk & 31) * 128 + t], tot);
    }
    if (t == 128) {
        float zs = zw[0] + zw[1] + zw[2] + zw[3];
        atomicAdd(&ws[WS_ZB + (blk & 63)], zs);
    }
}

// ---------------- K5: normalize + write outputs ----------------
__global__ __launch_bounds__(256) void k5_final(const float* __restrict__ ws,
                                                float* __restrict__ out) {
    int t = threadIdx.x, blk = blockIdx.x;
    float z = ws[WS_ZB + (t & 63)];
    for (int off = 1; off < 64; off <<= 1) z += __shfl_xor(z, off);
    float invZ = 1.0f / z;
    if (blk < 1024) {
        int i = blk * 256 + t;
        out[128 + i] = ws[WS_WEXP + i] * invZ;
    } else if (t < 128) {
        float s = 0.f;
#pragma unroll
        for (int b = 0; b < 32; ++b) s += ws[WS_GEB + b * 128 + t];
        out[t] = s * invZ;
    }
}

extern "C" void kernel_launch(void* const* d_in, const int* in_sizes, int n_in,
                              void* d_out, int out_size, void* d_ws, size_t ws_size,
                              hipStream_t stream) {
    const float* E   = (const float*)d_in[0];
    const float* v   = (const float*)d_in[1];
    const float* Wc1 = (const float*)d_in[2];
    const float* bc1 = (const float*)d_in[3];
    const float* Wc2 = (const float*)d_in[4];
    const float* bc2 = (const float*)d_in[5];
    const float* wpa = (const float*)d_in[6];
    const float* bpa = (const float*)d_in[7];
    const float* wvc = (const float*)d_in[8];
    const float* bvc = (const float*)d_in[9];
    float* ws  = (float*)d_ws;
    float* out = (float*)d_out;

    k2_stats<<<1024, 256, 0, stream>>>(E, v, wpa, bpa, Wc1, Wc2, bc1, bc2, ws);
    k2b_reduce<<<129, 256, 0, stream>>>(ws);
    k4_main<<<1024, 256, 0, stream>>>(wvc, bvc, Wc2, ws);
    k5_final<<<1025, 256, 0, stream>>>(ws, out);
}

// Round 9
// 253.511 us; speedup vs baseline: 1.0814x; 1.0254x over previous
//
#include <hip/hip_runtime.h>
#include <hip/hip_bf16.h>

#define DIM 128

typedef __attribute__((ext_vector_type(8))) short bf16x8;
typedef __attribute__((ext_vector_type(4))) float f32x4;

// ---- ws layout (float offsets) ----
#define WS_B12    0        // 128
#define WS_C      128      // 128  (unused; layout stability)
#define WS_SUMEE  256      // 128
#define WS_S      384      // 1
#define WS_ZB     416      // 64   Z buckets (atomic, 64-way)
#define WS_GEB    512      // 32*128 ge buckets (atomic, 32-way)
#define WS_WBF    4608     // 32768 bf16: Wcat[n][k]
#define WS_EEP    20992    // 128*1024 sum_eE partials
#define WS_SEP    152064   // 1024 S partials
#define WS_SP     153088   // N
#define WS_E      415232   // N
#define WS_WEXP   677376   // N
#define WS_EBF    939520   // N*128 bf16 (row-major), 64 MB

__device__ __forceinline__ unsigned short f2bf(float f) {
    union { float f; unsigned u; } v; v.f = f;
    unsigned r = v.u + 0x7fffu + ((v.u >> 16) & 1u);
    return (unsigned short)(r >> 16);
}

__device__ __forceinline__ float bfbits(unsigned u) {
    union { unsigned u; float f; } v; v.u = u;
    return v.f;
}

__device__ __forceinline__ unsigned pkbf(float a, float b) {
    union { __hip_bfloat162 h; unsigned u; } cv;
    cv.h = __float22bfloat162_rn(make_float2(a, b));
    return cv.u;
}

// ---------------- K2: one pass over E -> sp, e, bf16(E), per-block {S, sum_eE} partials ----------------
__global__ __launch_bounds__(256) void k2_stats(const float* __restrict__ E,
                                                const float* __restrict__ v,
                                                const float* __restrict__ wpa,
                                                const float* __restrict__ bpa,
                                                const float* __restrict__ Wc1,
                                                const float* __restrict__ Wc2,
                                                const float* __restrict__ bc1,
                                                const float* __restrict__ bc2,
                                                float* __restrict__ ws) {
    __shared__ float red[16][128];
    __shared__ float redS[16];
    int t = threadIdx.x;

    // ---- folded k1: weight conversion + bucket zero-init
    int gid = blockIdx.x * 256 + t;
    unsigned short* wbf_w = (unsigned short*)(ws + WS_WBF);
    if (gid < 32768) {
        int n = gid >> 7, k = gid & 127;
        float val = (n < 128) ? Wc1[n * 128 + k] : Wc2[(n - 128) * 128 + k];
        wbf_w[gid] = f2bf(val);
    }
    if (gid < 4096) ws[WS_GEB + gid] = 0.f;
    if (gid < 128) ws[WS_B12 + gid] = bc1[gid] + bc2[gid];
    if (gid < 64) ws[WS_ZB + gid] = 0.f;

    int wave = t >> 6, lane = t & 63;
    int cl = lane & 15, rs = lane >> 4;
    int row0 = blockIdx.x * 256;
    const float4* E4 = (const float4*)E;
    unsigned short* ebf = (unsigned short*)(ws + WS_EBF);

    float4 va = ((const float4*)v)[cl];
    float4 vb = ((const float4*)v)[16 + cl];
    float4 pa = ((const float4*)wpa)[cl];
    float4 pb = ((const float4*)wpa)[16 + cl];
    float bias = bpa[0];

    float4 acc0 = {0.f, 0.f, 0.f, 0.f}, acc1 = {0.f, 0.f, 0.f, 0.f};
    float se = 0.f;
    float* sp_ws = ws + WS_SP;
    float* e_ws = ws + WS_E;

#pragma unroll 8
    for (int it = 0; it < 16; ++it) {
        int row = row0 + it * 16 + wave * 4 + rs;
        float4 x0 = E4[row * 32 + cl];
        float4 x1 = E4[row * 32 + 16 + cl];
        unsigned p0 = pkbf(x0.x, x0.y);
        unsigned p1 = pkbf(x0.z, x0.w);
        unsigned p2 = pkbf(x1.x, x1.y);
        unsigned p3 = pkbf(x1.z, x1.w);
        *(uint2*)(ebf + (size_t)row * 128 + cl * 4) = make_uint2(p0, p1);
        *(uint2*)(ebf + (size_t)row * 128 + 64 + cl * 4) = make_uint2(p2, p3);

        float dv = x0.x * va.x + x0.y * va.y + x0.z * va.z + x0.w * va.w
                 + x1.x * vb.x + x1.y * vb.y + x1.z * vb.z + x1.w * vb.w;
        float dp = x0.x * pa.x + x0.y * pa.y + x0.z * pa.z + x0.w * pa.w
                 + x1.x * pb.x + x1.y * pb.y + x1.z * pb.z + x1.w * pb.w;
        for (int off = 1; off < 16; off <<= 1) {
            dv += __shfl_xor(dv, off);
            dp += __shfl_xor(dp, off);
        }
        float e = __expf(dp + bias);
        if (cl == 0) {
            sp_ws[row] = dv;
            e_ws[row] = e;
            se += e;
        }
        acc0.x += e * x0.x; acc0.y += e * x0.y; acc0.z += e * x0.z; acc0.w += e * x0.w;
        acc1.x += e * x1.x; acc1.y += e * x1.y; acc1.z += e * x1.z; acc1.w += e * x1.w;
    }
    int rr = wave * 4 + rs;
    float* dst = red[rr];
    dst[cl * 4 + 0] = acc0.x; dst[cl * 4 + 1] = acc0.y;
    dst[cl * 4 + 2] = acc0.z; dst[cl * 4 + 3] = acc0.w;
    dst[64 + cl * 4 + 0] = acc1.x; dst[64 + cl * 4 + 1] = acc1.y;
    dst[64 + cl * 4 + 2] = acc1.z; dst[64 + cl * 4 + 3] = acc1.w;
    if (cl == 0) redS[rr] = se;
    __syncthreads();
    if (t < 128) {
        float s = 0.f;
#pragma unroll
        for (int r = 0; r < 16; ++r) s += red[r][t];
        ws[WS_EEP + t * 1024 + blockIdx.x] = s;
    }
    if (t == 0) {
        float s = 0.f;
#pragma unroll
        for (int r = 0; r < 16; ++r) s += redS[r];
        ws[WS_SEP + blockIdx.x] = s;
    }
}

// ---------------- K2b: reduce partials -> SUMEE[128], S ----------------
__global__ __launch_bounds__(256) void k2b_reduce(float* __restrict__ ws) {
    __shared__ float r4[4];
    int t = threadIdx.x, blk = blockIdx.x;
    const float* src = (blk < 128) ? (ws + WS_EEP + blk * 1024) : (ws + WS_SEP);
    float s = src[t] + src[t + 256] + src[t + 512] + src[t + 768];
    for (int off = 1; off < 64; off <<= 1) s += __shfl_xor(s, off);
    if ((t & 63) == 0) r4[t >> 6] = s;
    __syncthreads();
    if (t == 0) {
        float tot = r4[0] + r4[1] + r4[2] + r4[3];
        if (blk < 128) ws[WS_SUMEE + blk] = tot;
        else ws[WS_S] = tot;
    }
}

// ---------------- K4: 4-wave transposed MFMA GEMM, 8 tiles/block, 1 barrier/tile ----------------
// 512 blocks x 256 thr: HALVES per-block overhead count vs r8 (prologue aw/c/stage
// latency chains ~2-2.5Kcy each + atomic tails) at identical occupancy (2 blocks/CU).
// ed LDS machinery removed: e read directly from e_ws (4 broadcast scalar loads issued
// at iter top, L2-hot, consumed ~1.5Kcy later); dinv computed per-use off critical path.
// Triple-buffered Elds, dbuf pim (safety over 8 iters: writes to buf[(it+1)%3] at iter
// it land after B1(it-1); last reads of that buffer (tile it-2) ended before B1(it-2)).
__global__ __launch_bounds__(256, 2) void k4_main(const float* __restrict__ wvc,
                                                  const float* __restrict__ bvc_p,
                                                  const float* __restrict__ Wc2,
                                                  float* __restrict__ ws) {
    __shared__ unsigned short Elds[3][64 * 136];   // 3 x 17,408 B
    __shared__ __align__(16) float arena[644];
    // loop-phase:  pim2 = arena[0..511] ([2][64][4]); c_lds = arena[512..639]
    // final-phase: gep  = arena[0..511] ([4][128]); zw = arena[640..643]
    float* pim2  = arena;
    float* c_lds = arena + 512;
    float* zw    = arena + 640;
    float* gep_a = arena;

    int t = threadIdx.x;
    int w = t >> 6, lane = t & 63, cl = lane & 15, q = lane >> 4;
    int blk = blockIdx.x;
    int row_base = blk * 512;                    // 8 tiles x 64 rows
    const unsigned short* wbf = (const unsigned short*)(ws + WS_WBF);
    const unsigned short* EbBase = (const unsigned short*)(ws + WS_EBF);
    const float* e_ws = ws + WS_E;

    float bvc = bvc_p[0];
    float Sv = ws[WS_S];
    int r0 = w * 16 + q * 4;                     // this lane's 4 rows within a tile
    int sr0 = t >> 4,           sc0 = t & 15;
    int sr1 = (t + 256) >> 4,   sc1 = (t + 256) & 15;
    int sr2 = (t + 512) >> 4,   sc2 = (t + 512) & 15;
    int sr3 = (t + 768) >> 4,   sc3 = (t + 768) & 15;

    // A fragments: wave w owns j-tiles {2w, 2w+1} for BOTH W_c1 and W_c2
    bf16x8 aw[2][2][4];   // [jt][0=W1,1=W2][kt]
#pragma unroll
    for (int jt = 0; jt < 2; ++jt) {
#pragma unroll
        for (int kt = 0; kt < 4; ++kt) {
            int jrow = w * 32 + jt * 16 + cl;
            aw[jt][0][kt] = *(const bf16x8*)(wbf + jrow * 128 + kt * 32 + q * 8);
            aw[jt][1][kt] = *(const bf16x8*)(wbf + (128 + jrow) * 128 + kt * 32 + q * 8);
        }
    }

    // per-lane j-row constants: j = w*32 + jt*16 + q*4 + reg
    float b12r[2][4], wvr[2][4];
#pragma unroll
    for (int jt = 0; jt < 2; ++jt)
#pragma unroll
        for (int reg = 0; reg < 4; ++reg) {
            int jr = w * 32 + jt * 16 + q * 4 + reg;
            b12r[jt][reg] = ws[WS_B12 + jr];
            wvr[jt][reg] = wvc[jr];
        }

    // folded k3: c[j] = Wc2[j,:] . sumEE
    if (t < 128) {
        const float4* row = (const float4*)(Wc2 + t * 128);
        const float4* se4 = (const float4*)(ws + WS_SUMEE);
        float4 s4 = {0.f, 0.f, 0.f, 0.f};
#pragma unroll
        for (int k = 0; k < 32; ++k) {
            float4 a = row[k], b = se4[k];
            s4.x += a.x * b.x; s4.y += a.y * b.y; s4.z += a.z * b.z; s4.w += a.w * b.w;
        }
        c_lds[t] = s4.x + s4.y + s4.z + s4.w;
    }

    // stage tile 0 -> buf 0; issue tile-1 loads (held across barrier)
    {
        const unsigned short* Eb0 = EbBase + (size_t)row_base * 128;
        uint4 a0 = *(const uint4*)(Eb0 + t * 8);
        uint4 a1 = *(const uint4*)(Eb0 + (t + 256) * 8);
        uint4 a2 = *(const uint4*)(Eb0 + (t + 512) * 8);
        uint4 a3 = *(const uint4*)(Eb0 + (t + 768) * 8);
        *(uint4*)&Elds[0][sr0 * 136 + sc0 * 8] = a0;
        *(uint4*)&Elds[0][sr1 * 136 + sc1 * 8] = a1;
        *(uint4*)&Elds[0][sr2 * 136 + sc2 * 8] = a2;
        *(uint4*)&Elds[0][sr3 * 136 + sc3 * 8] = a3;
    }
    uint4 sN0, sN1, sN2, sN3;
    {
        const unsigned short* Eb1 = EbBase + (size_t)(row_base + 64) * 128;
        sN0 = *(const uint4*)(Eb1 + t * 8);
        sN1 = *(const uint4*)(Eb1 + (t + 256) * 8);
        sN2 = *(const uint4*)(Eb1 + (t + 512) * 8);
        sN3 = *(const uint4*)(Eb1 + (t + 768) * 8);
    }
    __syncthreads();   // B_pro: buf0/c_lds visible

    float cjr[2][4];
#pragma unroll
    for (int jt = 0; jt < 2; ++jt)
#pragma unroll
        for (int reg = 0; reg < 4; ++reg)
            cjr[jt][reg] = c_lds[w * 32 + jt * 16 + q * 4 + reg];

    float z_lane = 0.f;
    float acc8[8] = {0.f, 0.f, 0.f, 0.f, 0.f, 0.f, 0.f, 0.f};

    for (int it = 0; it < 8; ++it) {
        int cur = it % 3;
        int pb = it & 1;
        int trow0 = row_base + it * 64;

        // write tile it+1 (regs loaded at it-1 / prologue)
        if (it < 7) {
            int wr = (it + 1) % 3;
            *(uint4*)&Elds[wr][sr0 * 136 + sc0 * 8] = sN0;
            *(uint4*)&Elds[wr][sr1 * 136 + sc1 * 8] = sN1;
            *(uint4*)&Elds[wr][sr2 * 136 + sc2 * 8] = sN2;
            *(uint4*)&Elds[wr][sr3 * 136 + sc3 * 8] = sN3;
        }
        // issue loads for tile it+2
        if (it < 6) {
            const unsigned short* EbN = EbBase + (size_t)(trow0 + 128) * 128;
            sN0 = *(const uint4*)(EbN + t * 8);
            sN1 = *(const uint4*)(EbN + (t + 256) * 8);
            sN2 = *(const uint4*)(EbN + (t + 512) * 8);
            sN3 = *(const uint4*)(EbN + (t + 768) * 8);
        }
        float4 sp4 = *(const float4*)&ws[WS_SP + trow0 + r0];
        // e for this lane's epilogue cols (broadcast scalar loads, consumed ~1.5Kcy later)
        float evr[4];
#pragma unroll
        for (int rt = 0; rt < 4; ++rt) evr[rt] = e_ws[trow0 + rt * 16 + cl];

        // Transposed GEMM: 64 MFMA per wave
        f32x4 acc[4][2][2];
#pragma unroll
        for (int rt = 0; rt < 4; ++rt)
#pragma unroll
            for (int jt = 0; jt < 2; ++jt) {
                acc[rt][jt][0] = (f32x4){0.f, 0.f, 0.f, 0.f};
                acc[rt][jt][1] = (f32x4){0.f, 0.f, 0.f, 0.f};
            }
#pragma unroll
        for (int rt = 0; rt < 4; ++rt) {
            bf16x8 b[4];
#pragma unroll
            for (int kt = 0; kt < 4; ++kt)
                b[kt] = *(const bf16x8*)&Elds[cur][(rt * 16 + cl) * 136 + kt * 32 + q * 8];
#pragma unroll
            for (int kt = 0; kt < 4; ++kt) {
                acc[rt][0][0] = __builtin_amdgcn_mfma_f32_16x16x32_bf16(aw[0][0][kt], b[kt], acc[rt][0][0], 0, 0, 0);
                acc[rt][0][1] = __builtin_amdgcn_mfma_f32_16x16x32_bf16(aw[0][1][kt], b[kt], acc[rt][0][1], 0, 0, 0);
                acc[rt][1][0] = __builtin_amdgcn_mfma_f32_16x16x32_bf16(aw[1][0][kt], b[kt], acc[rt][1][0], 0, 0, 0);
                acc[rt][1][1] = __builtin_amdgcn_mfma_f32_16x16x32_bf16(aw[1][1][kt], b[kt], acc[rt][1][1], 0, 0, 0);
            }
        }

        // Epilogue: i = rt*16 + cl, j = w*32 + jt*16 + q*4 + reg
#pragma unroll
        for (int rt = 0; rt < 4; ++rt) {
            float e_v = evr[rt];
            float di_v = 1.0f / (Sv - e_v);
            float p = 0.f;
#pragma unroll
            for (int jt = 0; jt < 2; ++jt)
#pragma unroll
                for (int reg = 0; reg < 4; ++reg) {
                    float h = acc[rt][jt][0][reg] + b12r[jt][reg]
                            + (cjr[jt][reg] - e_v * acc[rt][jt][1][reg]) * di_v;
                    p = fmaf(wvr[jt][reg], fmaxf(h, 0.f), p);
                }
            p += __shfl_xor(p, 16);
            p += __shfl_xor(p, 32);
            if (lane < 16) pim2[(pb * 64 + rt * 16 + lane) * 4 + w] = p;
        }
        __syncthreads();   // B1: pim[pb] + Elds[(it+1)%3] visible; sole barrier this tile

        // wexp: 4 rows/lane; one float4 per row
        float we[4];
#pragma unroll
        for (int rr = 0; rr < 4; ++rr) {
            float4 P = *(const float4*)&pim2[(pb * 64 + r0 + rr) * 4];
            float pi = (P.x + P.y) + (P.z + P.w);
            float spv = (rr == 0) ? sp4.x : (rr == 1) ? sp4.y : (rr == 2) ? sp4.z : sp4.w;
            we[rr] = __expf(spv + bvc + pi);
            z_lane += we[rr];
        }
        if (cl == 0)
            *(float4*)&ws[WS_WEXP + trow0 + r0] = (float4){we[0], we[1], we[2], we[3]};

#pragma unroll
        for (int rr = 0; rr < 4; ++rr) {
            int r = r0 + rr;
            float wer = we[rr];
            uint4 u = *(const uint4*)&Elds[cur][r * 136 + cl * 8];
            acc8[0] += wer * bfbits(u.x << 16);
            acc8[1] += wer * bfbits(u.x & 0xffff0000u);
            acc8[2] += wer * bfbits(u.y << 16);
            acc8[3] += wer * bfbits(u.y & 0xffff0000u);
            acc8[4] += wer * bfbits(u.z << 16);
            acc8[5] += wer * bfbits(u.z & 0xffff0000u);
            acc8[6] += wer * bfbits(u.w << 16);
            acc8[7] += wer * bfbits(u.w & 0xffff0000u);
        }
        // no trailing barrier: triple-buffered Elds / dbuf pim keep next iter's writes
        // WAR-safe (separated from this iter's reads by the NEXT B1)
    }

    __syncthreads();   // all pim reads done -> arena reusable as gep/zw

    z_lane += __shfl_xor(z_lane, 16);
    z_lane += __shfl_xor(z_lane, 32);
    if (lane == 0) zw[w] = z_lane;

#pragma unroll
    for (int jj = 0; jj < 8; ++jj) {
        acc8[jj] += __shfl_xor(acc8[jj], 16);
        acc8[jj] += __shfl_xor(acc8[jj], 32);
    }
    if (lane < 16) {
        *(float4*)&gep_a[w * 128 + cl * 8] = (float4){acc8[0], acc8[1], acc8[2], acc8[3]};
        *(float4*)&gep_a[w * 128 + cl * 8 + 4] = (float4){acc8[4], acc8[5], acc8[6], acc8[7]};
    }
    __syncthreads();

    if (t < 128) {
        float tot = gep_a[t] + gep_a[128 + t] + gep_a[256 + t] + gep_a[384 + t];
        atomicAdd(&ws[WS_GEB + (blk & 31) * 128 + t], tot);
    }
    if (t == 128) {
        float zs = zw[0] + zw[1] + zw[2] + zw[3];
        atomicAdd(&ws[WS_ZB + (blk & 63)], zs);
    }
}

// ---------------- K5: normalize + write outputs ----------------
__global__ __launch_bounds__(256) void k5_final(const float* __restrict__ ws,
                                                float* __restrict__ out) {
    int t = threadIdx.x, blk = blockIdx.x;
    float z = ws[WS_ZB + (t & 63)];
    for (int off = 1; off < 64; off <<= 1) z += __shfl_xor(z, off);
    float invZ = 1.0f / z;
    if (blk < 1024) {
        int i = blk * 256 + t;
        out[128 + i] = ws[WS_WEXP + i] * invZ;
    } else if (t < 128) {
        float s = 0.f;
#pragma unroll
        for (int b = 0; b < 32; ++b) s += ws[WS_GEB + b * 128 + t];
        out[t] = s * invZ;
    }
}

extern "C" void kernel_launch(void* const* d_in, const int* in_sizes, int n_in,
                              void* d_out, int out_size, void* d_ws, size_t ws_size,
                              hipStream_t stream) {
    const float* E   = (const float*)d_in[0];
    const float* v   = (const float*)d_in[1];
    const float* Wc1 = (const float*)d_in[2];
    const float* bc1 = (const float*)d_in[3];
    const float* Wc2 = (const float*)d_in[4];
    const float* bc2 = (const float*)d_in[5];
    const float* wpa = (const float*)d_in[6];
    const float* bpa = (const float*)d_in[7];
    const float* wvc = (const float*)d_in[8];
    const float* bvc = (const float*)d_in[9];
    float* ws  = (float*)d_ws;
    float* out = (float*)d_out;

    k2_stats<<<1024, 256, 0, stream>>>(E, v, wpa, bpa, Wc1, Wc2, bc1, bc2, ws);
    k2b_reduce<<<129, 256, 0, stream>>>(ws);
    k4_main<<<512, 256, 0, stream>>>(wvc, bvc, Wc2, ws);
    k5_final<<<1025, 256, 0, stream>>>(ws, out);
}